// Round 8
// baseline (60.447 us; speedup 1.0000x reference)
//
#include <hip/hip_runtime.h>
#include <hip/hip_bf16.h>
#include <math.h>

#define LA 1536
#define LS 512
#define LT 2048
#define CC 256
#define NH 4
#define DKH 64
#define NB 4
#define NT (LT / 64)
#define NTA (LA / 64)     // 24 audio tiles
#define SZ ((size_t)NB * LT * CC)

// (1/sqrt(64)) * log2(e): softmax runs in exp2 domain, folded into Q
#define QSCALE 0.1803368801111244f

typedef _Float16 f16;
typedef __attribute__((ext_vector_type(8))) _Float16 f16x8;
typedef __attribute__((ext_vector_type(4))) _Float16 f16x4;
typedef __attribute__((ext_vector_type(4))) float f32x4;
typedef __attribute__((ext_vector_type(16))) float f32x16;

__device__ inline f16x8 cvt8(const float4 a, const float4 b) {
    f16x8 h;
    h[0] = (_Float16)a.x; h[1] = (_Float16)a.y; h[2] = (_Float16)a.z; h[3] = (_Float16)a.w;
    h[4] = (_Float16)b.x; h[5] = (_Float16)b.y; h[6] = (_Float16)b.z; h[7] = (_Float16)b.w;
    return h;
}

// K-row permutation for the 32x32 path: store key k at LDS row sigma(k),
// sigma = swap bits 2 and 3 (involution). Then the swapped-QK^T C-registers
// line up exactly with the PV B-fragment k-order -> P never leaves registers.
#define SIG(j) (((j) & ~12) | (((j) & 4) << 1) | (((j) & 8) >> 1))

// ---------------------------------------------------------------------------
// Kernel 1: fused QKV projection, fp16 MFMA (16x16x32), 128x64 tiles.
// Q gets QSCALE folded in. V transposed Vt[(b*NH+h)*DKH+d][l] via LDS.
// (unchanged from round 7 - proven)
// ---------------------------------------------------------------------------
__global__ __launch_bounds__(256) void qkv_mfma(
    const float* __restrict__ audio, const float* __restrict__ text,
    const float* __restrict__ Wq, const float* __restrict__ bq,
    const float* __restrict__ Wk, const float* __restrict__ bk,
    const float* __restrict__ Wv, const float* __restrict__ bv,
    f16* __restrict__ Qh, f16* __restrict__ Kh, f16* __restrict__ Vth)
{
    __shared__ f16 smem[128 * 64 + 64 * 64];
    f16* As = smem;
    f16* Bs = smem + 128 * 64;

    const int tid = threadIdx.x;
    const int w = tid >> 6, l = tid & 63;
    const int g = l >> 4, r = l & 15;

    const int m0 = blockIdx.x * 128;
    const int n0 = blockIdx.y * 64;
    const int mat = n0 >> 8;          // 0=Q 1=K 2=V
    const int ch0 = n0 & 255;

    const float* W    = (mat == 0) ? Wq : (mat == 1) ? Wk : Wv;
    const float* bias = (mat == 0) ? bq : (mat == 1) ? bk : bv;

    const int b  = m0 >> 11;
    const int l0 = m0 & 2047;

    f32x4 acc[2][4] = {};

    for (int k0 = 0; k0 < CC; k0 += 64) {
        #pragma unroll
        for (int m = 0; m < 4; ++m) {
            const int idx = m * 256 + tid;
            const int row = idx >> 3, c = idx & 7;
            const int lrow = l0 + row;
            const float* src = (lrow < LA)
                ? (audio + ((size_t)b * LA + lrow) * CC + k0 + c * 8)
                : (text  + ((size_t)b * LS + (lrow - LA)) * CC + k0 + c * 8);
            const float4 x0 = *(const float4*)src;
            const float4 x1 = *(const float4*)(src + 4);
            *(f16x8*)(As + row * 64 + ((c ^ (row & 7)) << 3)) = cvt8(x0, x1);
        }
        #pragma unroll
        for (int m = 0; m < 2; ++m) {
            const int idx = m * 256 + tid;
            const int row = idx >> 3, c = idx & 7;
            const float* src = W + (size_t)(ch0 + row) * CC + k0 + c * 8;
            const float4 x0 = *(const float4*)src;
            const float4 x1 = *(const float4*)(src + 4);
            *(f16x8*)(Bs + row * 64 + ((c ^ (row & 7)) << 3)) = cvt8(x0, x1);
        }
        __syncthreads();
        #pragma unroll
        for (int kc = 0; kc < 2; ++kc) {
            f16x8 af[2];
            #pragma unroll
            for (int i = 0; i < 2; ++i) {
                const int row = w * 32 + i * 16 + r;
                const int c = kc * 4 + g;
                af[i] = *(const f16x8*)(As + row * 64 + ((c ^ (row & 7)) << 3));
            }
            f16x8 bf[4];
            #pragma unroll
            for (int j = 0; j < 4; ++j) {
                const int row = j * 16 + r;
                const int c = kc * 4 + g;
                bf[j] = *(const f16x8*)(Bs + row * 64 + ((c ^ (row & 7)) << 3));
            }
            #pragma unroll
            for (int i = 0; i < 2; ++i)
                #pragma unroll
                for (int j = 0; j < 4; ++j)
                    acc[i][j] = __builtin_amdgcn_mfma_f32_16x16x32_f16(af[i], bf[j], acc[i][j], 0, 0, 0);
        }
        __syncthreads();
    }

    float bcol[4];
    #pragma unroll
    for (int j = 0; j < 4; ++j) bcol[j] = bias[ch0 + j * 16 + r];

    if (mat <= 1) {
        f16* Out = (mat == 0) ? Qh : Kh;
        const float osc = (mat == 0) ? QSCALE : 1.0f;
        #pragma unroll
        for (int i = 0; i < 2; ++i)
            #pragma unroll
            for (int e = 0; e < 4; ++e) {
                const int m = m0 + w * 32 + i * 16 + g * 4 + e;
                #pragma unroll
                for (int j = 0; j < 4; ++j)
                    Out[(size_t)m * CC + ch0 + j * 16 + r] =
                        (_Float16)((acc[i][j][e] + bcol[j]) * osc);
            }
    } else {
        f16* Ts = smem;
        #pragma unroll
        for (int i = 0; i < 2; ++i)
            #pragma unroll
            for (int e = 0; e < 4; ++e) {
                const int ml = w * 32 + i * 16 + g * 4 + e;
                #pragma unroll
                for (int j = 0; j < 4; ++j)
                    Ts[(j * 16 + r) * 136 + ml] = (_Float16)(acc[i][j][e] + bcol[j]);
            }
        __syncthreads();
        const int b2 = m0 >> 11, l0m = m0 & 2047;
        #pragma unroll
        for (int u = 0; u < 4; ++u) {
            const int idx = u * 256 + tid;
            const int nl = idx >> 4, mc = idx & 15;
            const f16x8 vv = *(const f16x8*)(Ts + nl * 136 + mc * 8);
            const int nglob = ch0 + nl;
            const int hh = nglob >> 6, dd = nglob & 63;
            *(f16x8*)(Vth + ((size_t)((b2 * NH + hh) * DKH + dd)) * LT + l0m + mc * 8) = vv;
        }
    }
}

// ---------------------------------------------------------------------------
// Kernel 2: flash attention on 32x32x16 MFMA (2x FLOP per LDS byte).
// Block 256 thr = 2 tile-split groups x 2 waves; each wave owns 32 q-rows.
// Swapped QK^T: S^T = mfma(K_sigma, Q) -> lane holds 32 scores of ONE q-row
// (partner lane^32 has the complement) -> 1-shfl reduces; sc/inv lane-local.
// sigma row-permutation makes QK^T output registers = PV B-frag (P in regs).
// Single-buffered K/V per group (32 KB LDS), 2 barriers/iter.
// exp2-domain softmax (QSCALE pre-folded), defer-rescale, tile skipping.
// ---------------------------------------------------------------------------
__global__ __launch_bounds__(256, 4) void attn_f16(
    const f16* __restrict__ Q, const f16* __restrict__ K,
    const f16* __restrict__ Vt,
    const int* __restrict__ slen, const int* __restrict__ tlen,
    f16* __restrict__ AO)
{
    __shared__ __align__(16) f16 Ks[2][4096];    // [group][row_sigma*64 + d'], swizzled
    __shared__ __align__(16) f16 Vts[2][4096];   // [group][d*64 + key'], swizzled

    const int tid = threadIdx.x;
    const int w = tid >> 6, l = tid & 63;
    const int gid = w >> 1, qh = w & 1;
    const int lo = l & 31, hi = l >> 5;

    const int q0 = blockIdx.x * 64;
    const int h  = blockIdx.y;
    const int b  = blockIdx.z;

    const int ilen = slen[b];
    const int kcap = LA + tlen[b];
    const int nskip = ilen >> 6;
    int ntskip = 0;
    if (q0 >= LA) {
        const int skipmax = min(q0 - 63, kcap - 64);
        const int d = skipmax - LA;
        ntskip = (d < 0) ? 0 : ((d >> 6) + 1);
    }
    const int nAudio = NTA - nskip;                  // >= 1
    const int nProc  = nAudio + (NT - NTA) - ntskip; // >= 2
    const int nIter  = (nProc + 1) >> 1;

    const int qrow = q0 + 32 * qh + lo;    // this lane's q (all 32 scores)

    // Q B-fragments (QSCALE pre-folded): lane holds Q[qrow][16c + 8hi + e]
    f16x8 qf[4];
    #pragma unroll
    for (int c = 0; c < 4; ++c)
        qf[c] = *(const f16x8*)(Q + ((size_t)(b * LT) + qrow) * CC + h * DKH + 16 * c + 8 * hi);

    // staging coords: lane covers (sub-row l>>3, chunk l&7); wave does 4 blocks
    const int srw = l >> 3, scc = l & 7;

    #define TILE_OF(p) ((p) < nAudio ? (nskip + (p)) : (NTA + ntskip + ((p) - nAudio)))

    float m_run = -1e30f, l_run = 0.0f;
    f32x16 o[2] = {};   // o[dh][reg]: O^T[d = 32dh + (reg&3)+8*(reg>>2)+4hi][qrow]

    for (int i = 0; i < nIter; ++i) {
        const int pcur = 2 * i + gid;
        const bool curV = pcur < nProc;

        __syncthreads();                 // A: prev iter's LDS reads done
        if (curV) {                      // stage current tile (reg-staged)
            const int k0 = TILE_OF(pcur) * 64;
            f16x8 kreg[4], vreg[4];
            #pragma unroll
            for (int t = 0; t < 4; ++t) {
                const int sr = 8 * (4 * qh + t) + srw;
                kreg[t] = *(const f16x8*)(K + ((size_t)(b * LT) + k0 + sr) * CC + h * DKH + scc * 8);
                vreg[t] = *(const f16x8*)(Vt + ((size_t)((b * NH + h) * DKH) + sr) * LT + k0 + scc * 8);
            }
            #pragma unroll
            for (int t = 0; t < 4; ++t) {
                const int sr = 8 * (4 * qh + t) + srw;
                const int kr = SIG(sr);
                *(f16x8*)(Ks[gid] + kr * 64 + ((scc ^ (kr & 7)) << 3)) = kreg[t];
                *(f16x8*)(Vts[gid] + sr * 64 + ((scc ^ (sr & 7)) << 3)) = vreg[t];
            }
        }
        __syncthreads();                 // B: tile visible to both group waves

        if (curV) {
            const int kt = TILE_OF(pcur);
            const int k0 = kt * 64;
            const f16* Kb = Ks[gid];
            const f16* Vb = Vts[gid];

            // ---- S^T = K . Q^T  (two 32-key halves)
            f32x16 s0 = {}, s1 = {};
            #pragma unroll
            for (int c = 0; c < 4; ++c) {
                const int cc = 2 * c + hi;
                const int r0 = lo;
                const f16x8 a0 = *(const f16x8*)(Kb + r0 * 64 + ((cc ^ (r0 & 7)) << 3));
                s0 = __builtin_amdgcn_mfma_f32_32x32x16_f16(a0, qf[c], s0, 0, 0, 0);
                const int r1 = 32 + lo;
                const f16x8 a1 = *(const f16x8*)(Kb + r1 * 64 + ((cc ^ (r1 & 7)) << 3));
                s1 = __builtin_amdgcn_mfma_f32_32x32x16_f16(a1, qf[c], s1, 0, 0, 0);
            }

            // ---- mask in place. key(u) = k0 +32*(u>>4)+16*((u>>3)&1)+8hi+4*((u>>2)&1)+(u&3)
            const int mode = (kt < NTA) ? ((k0 >= ilen) ? 0 : 1)
                                        : ((q0 < LA) ? 0 : 2);
            if (mode == 1) {
                #pragma unroll
                for (int reg = 0; reg < 16; ++reg) {
                    const int kk0 = k0 + 16 * ((reg >> 3) & 1) + 8 * hi + 4 * ((reg >> 2) & 1) + (reg & 3);
                    if (kk0 < ilen)      s0[reg] = -INFINITY;
                    if (kk0 + 32 < ilen) s1[reg] = -INFINITY;
                }
            } else if (mode == 2) {
                #pragma unroll
                for (int reg = 0; reg < 16; ++reg) {
                    const int kk0 = k0 + 16 * ((reg >> 3) & 1) + 8 * hi + 4 * ((reg >> 2) & 1) + (reg & 3);
                    if (!(kk0 > qrow || kk0 >= kcap))           s0[reg] = -INFINITY;
                    const int kk1 = kk0 + 32;
                    if (!(kk1 > qrow || kk1 >= kcap))           s1[reg] = -INFINITY;
                }
            }

            // ---- online softmax (exp2 domain, finite sentinel, 1-shfl reduce)
            float mloc = -1e30f;
            #pragma unroll
            for (int reg = 0; reg < 16; ++reg) {
                mloc = fmaxf(mloc, s0[reg]);
                mloc = fmaxf(mloc, s1[reg]);
            }
            mloc = fmaxf(mloc, __shfl_xor(mloc, 32));
            const float m_new = fmaxf(m_run, mloc);

            // exp + pack PV B-frags directly (P stays in registers)
            // pb[kp][e] = P(kh = kp>>1, reg = 8*(kp&1) + 4*(e>>2) + (e&3))
            float ssum = 0.0f;
            f16x8 pb[4];
            #pragma unroll
            for (int kp = 0; kp < 4; ++kp)
                #pragma unroll
                for (int e = 0; e < 8; ++e) {
                    const int reg = 8 * (kp & 1) + 4 * (e >> 2) + (e & 3);
                    const float sval = (kp < 2) ? s0[reg] : s1[reg];
                    const float p = exp2f(sval - m_new);     // exp2(-inf)=0
                    pb[kp][e] = (_Float16)p;
                    ssum += p;
                }
            ssum += __shfl_xor(ssum, 32);

            if (__all(m_new == m_run)) {         // exact defer (sc==1)
                l_run += ssum;
            } else {
                const float sc = exp2f(m_run - m_new);   // lane-local: same q!
                l_run = l_run * sc + ssum;
                m_run = m_new;
                #pragma unroll
                for (int dh = 0; dh < 2; ++dh)
                    #pragma unroll
                    for (int reg = 0; reg < 16; ++reg)
                        o[dh][reg] *= sc;
            }

            // ---- O^T += V^T . P^T   (A = Vt rows, B = pb registers)
            #pragma unroll
            for (int kp = 0; kp < 4; ++kp) {
                const int cc = 2 * kp + hi;
                #pragma unroll
                for (int dh = 0; dh < 2; ++dh) {
                    const int dr = 32 * dh + lo;
                    const f16x8 a = *(const f16x8*)(Vb + dr * 64 + ((cc ^ (dr & 7)) << 3));
                    o[dh] = __builtin_amdgcn_mfma_f32_32x32x16_f16(a, pb[kp], o[dh], 0, 0, 0);
                }
            }
        }
    }

    // ---- merge the two groups' partials (union over dead K/V buffers)
    float* OcF = (float*)&Ks[0][0];      // 16 KB: [(qh*2+dh)][lane][16 regs]
    float* ML1 = (float*)&Vts[0][0];     // [qh*32+lo][2]
    __syncthreads();                     // last iter's LDS reads done
    if (gid == 1) {
        #pragma unroll
        for (int dh = 0; dh < 2; ++dh)
            #pragma unroll
            for (int u4 = 0; u4 < 4; ++u4) {
                f32x4 v;
                #pragma unroll
                for (int v2 = 0; v2 < 4; ++v2) v[v2] = o[dh][4 * u4 + v2];
                *(f32x4*)(OcF + (((qh * 2 + dh) << 10) + (l << 4) + 4 * u4)) = v;
            }
        if (hi == 0) {
            ML1[(qh * 32 + lo) * 2 + 0] = m_run;
            ML1[(qh * 32 + lo) * 2 + 1] = l_run;
        }
    }
    __syncthreads();

    if (gid == 0) {
        const float m1 = ML1[(qh * 32 + lo) * 2 + 0];
        const float l1 = ML1[(qh * 32 + lo) * 2 + 1];
        const float mt = fmaxf(m_run, m1);
        const float c0 = exp2f(m_run - mt);
        const float c1 = exp2f(m1 - mt);
        const float inv = 1.0f / (l_run * c0 + l1 * c1);   // lane-local (one q)
        #pragma unroll
        for (int dh = 0; dh < 2; ++dh)
            #pragma unroll
            for (int u4 = 0; u4 < 4; ++u4) {
                f16x4 outv;
                #pragma unroll
                for (int v2 = 0; v2 < 4; ++v2) {
                    const int reg = 4 * u4 + v2;
                    const float val = (o[dh][reg] * c0
                                     + OcF[((qh * 2 + dh) << 10) + (l << 4) + reg] * c1) * inv;
                    outv[v2] = (_Float16)val;
                }
                *(f16x4*)(AO + ((size_t)(b * LT) + qrow) * CC + h * DKH
                          + 32 * dh + 8 * u4 + 4 * hi) = outv;
            }
    }
    #undef TILE_OF
}

// ---------------------------------------------------------------------------
// Kernel 3: output projection, fp16 MFMA (X already f16), fp32 out.
// (unchanged from round 7)
// ---------------------------------------------------------------------------
__global__ __launch_bounds__(256) void out_mfma(
    const f16* __restrict__ X, const float* __restrict__ Wo,
    const float* __restrict__ bo, float* __restrict__ Out)
{
    __shared__ f16 As[128 * 64];
    __shared__ f16 Bs[64 * 64];

    const int tid = threadIdx.x;
    const int w = tid >> 6, l = tid & 63;
    const int g = l >> 4, r = l & 15;

    const int m0 = blockIdx.x * 128;
    const int n0 = blockIdx.y * 64;

    f32x4 acc[2][4] = {};

    for (int k0 = 0; k0 < CC; k0 += 64) {
        #pragma unroll
        for (int m = 0; m < 4; ++m) {
            const int idx = m * 256 + tid;
            const int row = idx >> 3, c = idx & 7;
            *(f16x8*)(As + row * 64 + ((c ^ (row & 7)) << 3)) =
                *(const f16x8*)(X + (size_t)(m0 + row) * CC + k0 + c * 8);
        }
        #pragma unroll
        for (int m = 0; m < 2; ++m) {
            const int idx = m * 256 + tid;
            const int row = idx >> 3, c = idx & 7;
            const float* src = Wo + (size_t)(n0 + row) * CC + k0 + c * 8;
            const float4 x0 = *(const float4*)src;
            const float4 x1 = *(const float4*)(src + 4);
            *(f16x8*)(Bs + row * 64 + ((c ^ (row & 7)) << 3)) = cvt8(x0, x1);
        }
        __syncthreads();
        #pragma unroll
        for (int kc = 0; kc < 2; ++kc) {
            f16x8 af[2];
            #pragma unroll
            for (int i = 0; i < 2; ++i) {
                const int row = w * 32 + i * 16 + r;
                const int c = kc * 4 + g;
                af[i] = *(const f16x8*)(As + row * 64 + ((c ^ (row & 7)) << 3));
            }
            f16x8 bf[4];
            #pragma unroll
            for (int j = 0; j < 4; ++j) {
                const int row = j * 16 + r;
                const int c = kc * 4 + g;
                bf[j] = *(const f16x8*)(Bs + row * 64 + ((c ^ (row & 7)) << 3));
            }
            #pragma unroll
            for (int i = 0; i < 2; ++i)
                #pragma unroll
                for (int j = 0; j < 4; ++j)
                    acc[i][j] = __builtin_amdgcn_mfma_f32_16x16x32_f16(af[i], bf[j], acc[i][j], 0, 0, 0);
        }
        __syncthreads();
    }

    float bcol[4];
    #pragma unroll
    for (int j = 0; j < 4; ++j) bcol[j] = bo[n0 + j * 16 + r];

    #pragma unroll
    for (int i = 0; i < 2; ++i)
        #pragma unroll
        for (int e = 0; e < 4; ++e) {
            const int m = m0 + w * 32 + i * 16 + g * 4 + e;
            #pragma unroll
            for (int j = 0; j < 4; ++j)
                Out[(size_t)m * CC + n0 + j * 16 + r] = acc[i][j][e] + bcol[j];
        }
}

// ---------------------------------------------------------------------------
extern "C" void kernel_launch(void* const* d_in, const int* in_sizes, int n_in,
                              void* d_out, int out_size, void* d_ws, size_t ws_size,
                              hipStream_t stream)
{
    const float* audio = (const float*)d_in[0];
    const float* text  = (const float*)d_in[1];
    const int*   slen  = (const int*)d_in[2];
    const int*   tlen  = (const int*)d_in[3];
    const float* Wq = (const float*)d_in[4];
    const float* bq = (const float*)d_in[5];
    const float* Wk = (const float*)d_in[6];
    const float* bk = (const float*)d_in[7];
    const float* Wv = (const float*)d_in[8];
    const float* bv = (const float*)d_in[9];
    const float* Wo = (const float*)d_in[10];
    const float* bo = (const float*)d_in[11];
    float* out = (float*)d_out;

    f16* Qh  = (f16*)d_ws;
    f16* Kh  = Qh + SZ;
    f16* Vth = Kh + SZ;
    f16* AOh = Vth + SZ;

    qkv_mfma<<<dim3(64, 12), 256, 0, stream>>>(audio, text, Wq, bq, Wk, bk, Wv, bv,
                                               Qh, Kh, Vth);
    attn_f16<<<dim3(LT / 64, NH, NB), 256, 0, stream>>>(Qh, Kh, Vth, slen, tlen, AOh);
    out_mfma<<<dim3(64, 4), 256, 0, stream>>>(AOh, Wo, bo, out);
}